// Round 7
// baseline (1568.844 us; speedup 1.0000x reference)
//
#include <hip/hip_runtime.h>

#define HIDF 128
#define NSLICE 8
#define SLICEF 16

typedef float v4f __attribute__((ext_vector_type(4)));

static inline int cdiv(int a, int b) { return (a + b - 1) / b; }
static inline size_t alup(size_t b) { return (b + 255) & ~(size_t)255; }

// ---- degree count over dst ----
__global__ void k_deg(const int* __restrict__ dst, int E, int* __restrict__ deg) {
    int i = blockIdx.x * blockDim.x + threadIdx.x;
    if (i < E) atomicAdd(&deg[dst[i]], 1);
}

// ---- dinv = rsqrt(max(deg,1)); dinv2 = 1/max(deg,1); sdeg = sqrt(max(deg,1)) ----
__global__ void k_dinv(const int* __restrict__ deg, int N, float* __restrict__ dinv,
                       float* __restrict__ dinv2, float* __restrict__ sdeg) {
    int i = blockIdx.x * blockDim.x + threadIdx.x;
    if (i < N) {
        float d = fmaxf((float)deg[i], 1.0f);
        dinv[i] = rsqrtf(d);
        dinv2[i] = 1.0f / d;
        sdeg[i] = sqrtf(d);
    }
}

// ---- coefficients: cL[j]=gamma_L[j]; cH[j]=(-1)^j sum_{k>=j} gamma_H[k]*C(k,j) ----
__global__ void k_coef(const float* __restrict__ gL, const float* __restrict__ gH, int K,
                       float* __restrict__ cL, float* __restrict__ cH) {
    if (threadIdx.x == 0 && blockIdx.x == 0) {
        for (int j = 0; j <= K; ++j) {
            double s = 0.0;
            double C = 1.0;
            for (int k = j; k <= K; ++k) {
                s += (double)gH[k] * C;
                C = C * (double)(k + 1) / (double)(k + 1 - j);
            }
            cH[j] = (j & 1) ? (float)(-s) : (float)s;
            cL[j] = gL[j];
        }
    }
}

// ---- single-block exclusive scan deg -> row_ptr ----
__global__ __launch_bounds__(1024) void k_scan(const int* __restrict__ deg, int N,
                                               int* __restrict__ row_ptr) {
    __shared__ int ls[1024];
    int tid = threadIdx.x;
    int chunk = (N + 1023) / 1024;
    int start = tid * chunk;
    int end = min(start + chunk, N);
    int s = 0;
    for (int i = start; i < end; ++i) s += deg[i];
    ls[tid] = s;
    __syncthreads();
    for (int off = 1; off < 1024; off <<= 1) {
        int v = (tid >= off) ? ls[tid - off] : 0;
        __syncthreads();
        ls[tid] += v;
        __syncthreads();
    }
    int run = ls[tid] - s;
    for (int i = start; i < end; ++i) {
        row_ptr[i] = run;
        run += deg[i];
    }
    if (tid == 1023) row_ptr[N] = run;
}

// ---- scatter edges into CSR (by dst) ----
__global__ void k_scatter(const int* __restrict__ src, const int* __restrict__ dst, int E,
                          const int* __restrict__ row_ptr, int* __restrict__ fill,
                          const float* __restrict__ dinv, int* __restrict__ csr_src,
                          float* __restrict__ csr_w) {
    int i = blockIdx.x * blockDim.x + threadIdx.x;
    if (i < E) {
        int s = src[i], d = dst[i];
        int pos = row_ptr[d] + atomicAdd(&fill[d], 1);
        csr_src[pos] = s;
        csr_w[pos] = dinv[s] * dinv[d];
    }
}

// ---- input GEMM: H = X @ W + b ----
// mode 1 (deferred): write u0 = dinv*h SLICE-MAJOR. mode 0: row-major H + acc init.
__global__ __launch_bounds__(512) void k_gemm_in(
    const float* __restrict__ X, const float* __restrict__ W, const float* __restrict__ b,
    float* __restrict__ H, float* __restrict__ accL, float* __restrict__ accH,
    const float* __restrict__ cL, const float* __restrict__ cH,
    const float* __restrict__ dinv, int M, int Kdim, int mode) {
    const int BK = 20;
    __shared__ float As[BK][132];
    __shared__ float Bs[BK][128];
    int tid = threadIdx.x;
    int tx = tid & 31, ty = tid >> 5;  // ty 0..15
    int row0 = blockIdx.x * 128;
    float acc[8][4] = {};
    for (int k0 = 0; k0 < Kdim; k0 += BK) {
        for (int l = tid; l < 640; l += 512) {
            int m = l / 5, q = l % 5;
            int r = row0 + m;
            float4 v = {0.f, 0.f, 0.f, 0.f};
            if (r < M) v = *(const float4*)&X[(long)r * Kdim + k0 + q * 4];
            As[q * 4 + 0][m] = v.x;
            As[q * 4 + 1][m] = v.y;
            As[q * 4 + 2][m] = v.z;
            As[q * 4 + 3][m] = v.w;
        }
        for (int l = tid; l < 640; l += 512) {
            int k = l >> 5, n = (l & 31) * 4;
            *(float4*)&Bs[k][n] = *(const float4*)&W[(long)(k0 + k) * 128 + n];
        }
        __syncthreads();
#pragma unroll
        for (int k = 0; k < BK; ++k) {
            float4 a0 = *(const float4*)&As[k][ty * 8];
            float4 a1 = *(const float4*)&As[k][ty * 8 + 4];
            float4 bb = *(const float4*)&Bs[k][tx * 4];
            float a[8] = {a0.x, a0.y, a0.z, a0.w, a1.x, a1.y, a1.z, a1.w};
#pragma unroll
            for (int i = 0; i < 8; ++i) {
                acc[i][0] += a[i] * bb.x;
                acc[i][1] += a[i] * bb.y;
                acc[i][2] += a[i] * bb.z;
                acc[i][3] += a[i] * bb.w;
            }
        }
        __syncthreads();
    }
    float g0 = cL[0], h0 = cH[0];
    float4 bias = *(const float4*)&b[tx * 4];
    float bv[4] = {bias.x, bias.y, bias.z, bias.w};
    int f = tx * 4;
    long slice_off = (long)(f >> 4) * ((long)M * SLICEF) + (f & 15);
#pragma unroll
    for (int i = 0; i < 8; ++i) {
        int r = row0 + ty * 8 + i;
        if (r < M) {
            float4 vh;
            float* ph = (float*)&vh;
#pragma unroll
            for (int j = 0; j < 4; ++j) ph[j] = acc[i][j] + bv[j];
            if (mode == 1) {
                float dv = dinv[r];
                float4 u = {vh.x * dv, vh.y * dv, vh.z * dv, vh.w * dv};
                *(float4*)&H[slice_off + (long)r * SLICEF] = u;
            } else {
                long idx = (long)r * 128 + f;
                *(float4*)&H[idx] = vh;
                float4 vl = {g0 * vh.x, g0 * vh.y, g0 * vh.z, g0 * vh.w};
                float4 vv = {h0 * vh.x, h0 * vh.y, h0 * vh.z, h0 * vh.w};
                *(float4*)&accL[idx] = vl;
                *(float4*)&accH[idx] = vv;
            }
        }
    }
}

// ---- sliced prop: u_out[d] = dinv2[d] * sum_{s in N(d)} u_in[s], one 16-feat slice ----
// blockIdx.x = slice (0..7) -> XCD round-robin; blockIdx.y = node chunk.
// wave = 2 nodes (half-wave each); half = 8 edge-groups x 4 lanes (float4 of slice)
__global__ __launch_bounds__(256) void k_prop_slice(
    const int* __restrict__ row_ptr, const int* __restrict__ csr_src,
    const float* __restrict__ dinv2, const float* __restrict__ u_in,
    float* __restrict__ u_out, int N, int cpb) {
    int slice = blockIdx.x;
    long soff = (long)slice * ((long)N * SLICEF);
    int tid = threadIdx.x;
    int wave = tid >> 6;
    int lane = tid & 63;
    int half = lane >> 5;
    int h5 = lane & 31;
    int eg = h5 >> 2;   // 0..7 edge group
    int fc = h5 & 3;    // float4 chunk within slice
    int n0 = blockIdx.y * cpb;
    int n1 = min(N, n0 + cpb);
    const float* uin = u_in + soff + fc * 4;
    for (int nd = n0 + wave * 2 + half; nd < n1; nd += 8) {
        int e0 = row_ptr[nd], e1 = row_ptr[nd + 1];
        float4 s = {0.f, 0.f, 0.f, 0.f};
        int e = e0 + eg;
        for (; e + 8 < e1; e += 16) {
            int s0 = __builtin_nontemporal_load(&csr_src[e]);
            int s1 = __builtin_nontemporal_load(&csr_src[e + 8]);
            float4 v0 = *(const float4*)&uin[(long)s0 * SLICEF];
            float4 v1 = *(const float4*)&uin[(long)s1 * SLICEF];
            s.x += v0.x + v1.x;
            s.y += v0.y + v1.y;
            s.z += v0.z + v1.z;
            s.w += v0.w + v1.w;
        }
        if (e < e1) {
            int s0 = __builtin_nontemporal_load(&csr_src[e]);
            float4 v0 = *(const float4*)&uin[(long)s0 * SLICEF];
            s.x += v0.x;
            s.y += v0.y;
            s.z += v0.z;
            s.w += v0.w;
        }
        // reduce over the 8 edge groups (stay within the 32-lane half)
        s.x += __shfl_xor(s.x, 4); s.y += __shfl_xor(s.y, 4);
        s.z += __shfl_xor(s.z, 4); s.w += __shfl_xor(s.w, 4);
        s.x += __shfl_xor(s.x, 8); s.y += __shfl_xor(s.y, 8);
        s.z += __shfl_xor(s.z, 8); s.w += __shfl_xor(s.w, 8);
        s.x += __shfl_xor(s.x, 16); s.y += __shfl_xor(s.y, 16);
        s.z += __shfl_xor(s.z, 16); s.w += __shfl_xor(s.w, 16);
        if (eg == 0) {
            float d2 = dinv2[nd];
            v4f o = {s.x * d2, s.y * d2, s.z * d2, s.w * d2};
            __builtin_nontemporal_store(o, (v4f*)&u_out[soff + (long)nd * SLICEF + fc * 4]);
        }
    }
}

// ---- fallback prop (row-major, csr_w, acc RMW) ----
__global__ __launch_bounds__(256) void k_prop(
    const int* __restrict__ row_ptr, const int* __restrict__ csr_src,
    const float* __restrict__ csr_w, const float* __restrict__ t_in,
    float* __restrict__ t_out, float* __restrict__ accL, float* __restrict__ accH,
    const float* __restrict__ cL, const float* __restrict__ cH, int j, int N, int write_t,
    int do_acc) {
    int wave = threadIdx.x >> 6;
    int lane = threadIdx.x & 63;
    int half = lane >> 5;
    int l5 = lane & 31;
    int node = blockIdx.x * 4 + wave;
    if (node >= N) return;
    int e0 = row_ptr[node], e1 = row_ptr[node + 1];
    float sx = 0.f, sy = 0.f, sz = 0.f, sw = 0.f;
    int e = e0 + half;
    for (; e + 6 < e1; e += 8) {
        int i0 = csr_src[e], i1 = csr_src[e + 2], i2 = csr_src[e + 4], i3 = csr_src[e + 6];
        float w0 = csr_w[e], w1 = csr_w[e + 2], w2 = csr_w[e + 4], w3 = csr_w[e + 6];
        float4 v0 = *(const float4*)&t_in[(long)i0 * HIDF + l5 * 4];
        float4 v1 = *(const float4*)&t_in[(long)i1 * HIDF + l5 * 4];
        float4 v2 = *(const float4*)&t_in[(long)i2 * HIDF + l5 * 4];
        float4 v3 = *(const float4*)&t_in[(long)i3 * HIDF + l5 * 4];
        sx += w0 * v0.x + w1 * v1.x + w2 * v2.x + w3 * v3.x;
        sy += w0 * v0.y + w1 * v1.y + w2 * v2.y + w3 * v3.y;
        sz += w0 * v0.z + w1 * v1.z + w2 * v2.z + w3 * v3.z;
        sw += w0 * v0.w + w1 * v1.w + w2 * v2.w + w3 * v3.w;
    }
    for (; e < e1; e += 2) {
        int i0 = csr_src[e];
        float w0 = csr_w[e];
        float4 v0 = *(const float4*)&t_in[(long)i0 * HIDF + l5 * 4];
        sx += w0 * v0.x;
        sy += w0 * v0.y;
        sz += w0 * v0.z;
        sw += w0 * v0.w;
    }
    sx += __shfl_xor(sx, 32);
    sy += __shfl_xor(sy, 32);
    sz += __shfl_xor(sz, 32);
    sw += __shfl_xor(sw, 32);
    if (half == 0) {
        long base = (long)node * HIDF + l5 * 4;
        if (write_t) {
            float4 o = {sx, sy, sz, sw};
            *(float4*)&t_out[base] = o;
        }
        if (do_acc) {
            float gL = cL[j], gH = cH[j];
            float4 aL = *(const float4*)&accL[base];
            float4 aH = *(const float4*)&accH[base];
            aL.x += gL * sx; aL.y += gL * sy; aL.z += gL * sz; aL.w += gL * sw;
            aH.x += gH * sx; aH.y += gH * sy; aH.z += gH * sz; aH.w += gH * sw;
            *(float4*)&accL[base] = aL;
            *(float4*)&accH[base] = aH;
        }
    }
}

// ---- fused basis combine + BN stats (deferred path, slice-major basis) ----
// acc = sdeg[r] * sum_j c[j] * u_j[r]
__global__ __launch_bounds__(256) void k_combine(
    const float* __restrict__ tb, long tstride, int K, const float* __restrict__ sdeg,
    float* __restrict__ accL, float* __restrict__ accH, const float* __restrict__ cL,
    const float* __restrict__ cH, int N, float* __restrict__ sums) {
    int tid = threadIdx.x;
    int l5 = tid & 31;
    int g = tid >> 5;
    long N16 = (long)N * SLICEF;
    long boff = (long)(l5 >> 2) * N16 + (l5 & 3) * 4;
    float4 s1 = {0, 0, 0, 0}, s2 = {0, 0, 0, 0}, s3 = {0, 0, 0, 0}, s4 = {0, 0, 0, 0};
    for (long r = blockIdx.x * 8 + g; r < N; r += (long)gridDim.x * 8) {
        const float* p = tb + boff + r * SLICEF;
        float sd = sdeg[r];
        float4 aL = {0, 0, 0, 0}, aH = {0, 0, 0, 0};
        for (int j = 0; j <= K; ++j) {
            float4 v = *(const float4*)(p + (long)j * tstride);
            float gL = cL[j], gH = cH[j];
            aL.x += gL * v.x; aL.y += gL * v.y; aL.z += gL * v.z; aL.w += gL * v.w;
            aH.x += gH * v.x; aH.y += gH * v.y; aH.z += gH * v.z; aH.w += gH * v.w;
        }
        aL.x *= sd; aL.y *= sd; aL.z *= sd; aL.w *= sd;
        aH.x *= sd; aH.y *= sd; aH.z *= sd; aH.w *= sd;
        long base = r * HIDF + l5 * 4;
        *(float4*)&accL[base] = aL;
        *(float4*)&accH[base] = aH;
        s1.x += aL.x; s1.y += aL.y; s1.z += aL.z; s1.w += aL.w;
        s2.x += aL.x * aL.x; s2.y += aL.y * aL.y; s2.z += aL.z * aL.z; s2.w += aL.w * aL.w;
        s3.x += aH.x; s3.y += aH.y; s3.z += aH.z; s3.w += aH.w;
        s4.x += aH.x * aH.x; s4.y += aH.y * aH.y; s4.z += aH.z * aH.z; s4.w += aH.w * aH.w;
    }
    __shared__ float4 ls1[256], ls2[256], ls3[256], ls4[256];
    ls1[tid] = s1;
    ls2[tid] = s2;
    ls3[tid] = s3;
    ls4[tid] = s4;
    __syncthreads();
    if (tid < 32) {
        float4 a = ls1[tid], bq = ls2[tid], c = ls3[tid], d = ls4[tid];
        for (int gg = 1; gg < 8; ++gg) {
            float4 t;
            t = ls1[gg * 32 + tid]; a.x += t.x; a.y += t.y; a.z += t.z; a.w += t.w;
            t = ls2[gg * 32 + tid]; bq.x += t.x; bq.y += t.y; bq.z += t.z; bq.w += t.w;
            t = ls3[gg * 32 + tid]; c.x += t.x; c.y += t.y; c.z += t.z; c.w += t.w;
            t = ls4[gg * 32 + tid]; d.x += t.x; d.y += t.y; d.z += t.z; d.w += t.w;
        }
        // thread l5 covers global features l5*4..l5*4+3 (slice-major maps back linearly)
        int f = tid * 4;
        atomicAdd(&sums[f + 0], a.x); atomicAdd(&sums[f + 1], a.y);
        atomicAdd(&sums[f + 2], a.z); atomicAdd(&sums[f + 3], a.w);
        atomicAdd(&sums[128 + f + 0], bq.x); atomicAdd(&sums[128 + f + 1], bq.y);
        atomicAdd(&sums[128 + f + 2], bq.z); atomicAdd(&sums[128 + f + 3], bq.w);
        atomicAdd(&sums[256 + f + 0], c.x); atomicAdd(&sums[256 + f + 1], c.y);
        atomicAdd(&sums[256 + f + 2], c.z); atomicAdd(&sums[256 + f + 3], c.w);
        atomicAdd(&sums[384 + f + 0], d.x); atomicAdd(&sums[384 + f + 1], d.y);
        atomicAdd(&sums[384 + f + 2], d.z); atomicAdd(&sums[384 + f + 3], d.w);
    }
}

// ---- standalone BN stats (fallback path) ----
__global__ __launch_bounds__(256) void k_stats(const float* __restrict__ accL,
                                               const float* __restrict__ accH, int N,
                                               float* __restrict__ sums) {
    int tid = threadIdx.x;
    int l5 = tid & 31;
    int g = tid >> 5;
    float4 l1 = {0, 0, 0, 0}, l2 = {0, 0, 0, 0}, h1 = {0, 0, 0, 0}, h2 = {0, 0, 0, 0};
    for (int r = blockIdx.x * 8 + g; r < N; r += gridDim.x * 8) {
        float4 v = *(const float4*)&accL[(long)r * HIDF + l5 * 4];
        l1.x += v.x; l1.y += v.y; l1.z += v.z; l1.w += v.w;
        l2.x += v.x * v.x; l2.y += v.y * v.y; l2.z += v.z * v.z; l2.w += v.w * v.w;
        float4 u = *(const float4*)&accH[(long)r * HIDF + l5 * 4];
        h1.x += u.x; h1.y += u.y; h1.z += u.z; h1.w += u.w;
        h2.x += u.x * u.x; h2.y += u.y * u.y; h2.z += u.z * u.z; h2.w += u.w * u.w;
    }
    __shared__ float4 s1[256], s2[256], s3[256], s4[256];
    s1[tid] = l1; s2[tid] = l2; s3[tid] = h1; s4[tid] = h2;
    __syncthreads();
    if (tid < 32) {
        float4 a = s1[tid], bq = s2[tid], c = s3[tid], d = s4[tid];
        for (int gg = 1; gg < 8; ++gg) {
            float4 t;
            t = s1[gg * 32 + tid]; a.x += t.x; a.y += t.y; a.z += t.z; a.w += t.w;
            t = s2[gg * 32 + tid]; bq.x += t.x; bq.y += t.y; bq.z += t.z; bq.w += t.w;
            t = s3[gg * 32 + tid]; c.x += t.x; c.y += t.y; c.z += t.z; c.w += t.w;
            t = s4[gg * 32 + tid]; d.x += t.x; d.y += t.y; d.z += t.z; d.w += t.w;
        }
        int f = tid * 4;
        atomicAdd(&sums[f + 0], a.x); atomicAdd(&sums[f + 1], a.y);
        atomicAdd(&sums[f + 2], a.z); atomicAdd(&sums[f + 3], a.w);
        atomicAdd(&sums[128 + f + 0], bq.x); atomicAdd(&sums[128 + f + 1], bq.y);
        atomicAdd(&sums[128 + f + 2], bq.z); atomicAdd(&sums[128 + f + 3], bq.w);
        atomicAdd(&sums[256 + f + 0], c.x); atomicAdd(&sums[256 + f + 1], c.y);
        atomicAdd(&sums[256 + f + 2], c.z); atomicAdd(&sums[256 + f + 3], c.w);
        atomicAdd(&sums[384 + f + 0], d.x); atomicAdd(&sums[384 + f + 1], d.y);
        atomicAdd(&sums[384 + f + 2], d.z); atomicAdd(&sums[384 + f + 3], d.w);
    }
}

// ---- finalize BN affine for both encoders ----
__global__ void k_bnfin(const float* __restrict__ sums, int N, const float* __restrict__ scale,
                        const float* __restrict__ shift, float* __restrict__ a_mul,
                        float* __restrict__ a_add) {
    int f = threadIdx.x;
    for (int enc = 0; enc < 2; ++enc) {
        float mu = sums[enc * 256 + f] / (float)N;
        float var = sums[enc * 256 + 128 + f] / (float)N - mu * mu;
        float rstd = rsqrtf(var + 1e-5f);
        float am = rstd * scale[f];
        a_mul[enc * 128 + f] = am;
        a_add[enc * 128 + f] = shift[f] - mu * am;
    }
}

// ---- up GEMM, BN fused at staging, bias+relu; grid.y = encoder ----
__global__ __launch_bounds__(512) void k_gemm_up(
    const float* __restrict__ accL, const float* __restrict__ accH,
    const float* __restrict__ W, const float* __restrict__ bias,
    const float* __restrict__ a_mul, const float* __restrict__ a_add,
    float* __restrict__ out, int M) {
    int enc = blockIdx.y;
    const float* A = enc ? accH : accL;
    float* O = out + (size_t)enc * M * 128;
    __shared__ float As[16][132];
    __shared__ float Bs[16][128];
    __shared__ float ams[128], aas[128];
    int tid = threadIdx.x;
    int tx = tid & 31, ty = tid >> 5;
    int row0 = blockIdx.x * 128;
    if (tid < 128) {
        ams[tid] = a_mul[enc * 128 + tid];
        aas[tid] = a_add[enc * 128 + tid];
    }
    __syncthreads();
    float acc[8][4] = {};
    for (int k0 = 0; k0 < 128; k0 += 16) {
        {
            int m = tid >> 2, q = tid & 3;
            int r = row0 + m;
            float4 v = {0.f, 0.f, 0.f, 0.f};
            if (r < M) v = *(const float4*)&A[(long)r * 128 + k0 + q * 4];
            int kk = q * 4;
            As[kk + 0][m] = v.x * ams[k0 + kk + 0] + aas[k0 + kk + 0];
            As[kk + 1][m] = v.y * ams[k0 + kk + 1] + aas[k0 + kk + 1];
            As[kk + 2][m] = v.z * ams[k0 + kk + 2] + aas[k0 + kk + 2];
            As[kk + 3][m] = v.w * ams[k0 + kk + 3] + aas[k0 + kk + 3];
        }
        {
            int k = tid >> 5, n = (tid & 31) * 4;
            *(float4*)&Bs[k][n] = *(const float4*)&W[(long)(k0 + k) * 128 + n];
        }
        __syncthreads();
#pragma unroll
        for (int k = 0; k < 16; ++k) {
            float4 a0 = *(const float4*)&As[k][ty * 8];
            float4 a1 = *(const float4*)&As[k][ty * 8 + 4];
            float4 bb = *(const float4*)&Bs[k][tx * 4];
            float a[8] = {a0.x, a0.y, a0.z, a0.w, a1.x, a1.y, a1.z, a1.w};
#pragma unroll
            for (int i = 0; i < 8; ++i) {
                acc[i][0] += a[i] * bb.x;
                acc[i][1] += a[i] * bb.y;
                acc[i][2] += a[i] * bb.z;
                acc[i][3] += a[i] * bb.w;
            }
        }
        __syncthreads();
    }
    float4 bv = *(const float4*)&bias[tx * 4];
    float bb[4] = {bv.x, bv.y, bv.z, bv.w};
#pragma unroll
    for (int i = 0; i < 8; ++i) {
        int r = row0 + ty * 8 + i;
        if (r < M) {
            float4 o;
            o.x = fmaxf(acc[i][0] + bb[0], 0.0f);
            o.y = fmaxf(acc[i][1] + bb[1], 0.0f);
            o.z = fmaxf(acc[i][2] + bb[2], 0.0f);
            o.w = fmaxf(acc[i][3] + bb[3], 0.0f);
            *(float4*)&O[(long)r * 128 + tx * 4] = o;
        }
    }
}

extern "C" void kernel_launch(void* const* d_in, const int* in_sizes, int n_in, void* d_out,
                              int out_size, void* d_ws, size_t ws_size, hipStream_t stream) {
    const float* x = (const float*)d_in[0];
    const int* edge_index = (const int*)d_in[1];
    const float* W_in = (const float*)d_in[2];
    const float* b_in = (const float*)d_in[3];
    const float* gamma_L = (const float*)d_in[4];
    const float* gamma_H = (const float*)d_in[5];
    const float* bn_scale = (const float*)d_in[6];
    const float* bn_shift = (const float*)d_in[7];
    const float* W_up = (const float*)d_in[8];
    const float* b_up = (const float*)d_in[9];
    float* out = (float*)d_out;

    const int HID = in_sizes[3];       // 128
    const int IN = in_sizes[2] / HID;  // 500
    const int N = in_sizes[0] / IN;    // 50000
    const int E = in_sizes[1] / 2;     // 800000
    const int K = in_sizes[4] - 1;     // 10

    const int* src = edge_index;
    const int* dst = edge_index + E;

    char* base = (char*)d_ws;
    size_t off = 0;
    auto take = [&](size_t bytes) -> char* {
        char* r = base + off;
        off += alup(bytes);
        return r;
    };
    int* deg = (int*)take((size_t)N * 4);
    int* row_ptr = (int*)take((size_t)(N + 1) * 4);
    int* fill = (int*)take((size_t)N * 4);
    float* dinv = (float*)take((size_t)N * 4);
    float* dinv2 = (float*)take((size_t)N * 4);
    float* sdeg = (float*)take((size_t)N * 4);
    int* csr_src = (int*)take((size_t)E * 4);
    float* csr_w = (float*)take((size_t)E * 4);
    float* accL = (float*)take((size_t)N * HID * 4);
    float* accH = (float*)take((size_t)N * HID * 4);
    float* sums = (float*)take(512 * 4);
    float* cL = (float*)take(64 * 4);
    float* cH = (float*)take(64 * 4);
    float* a_mul = (float*)take(256 * 4);
    float* a_add = (float*)take(256 * 4);
    size_t per = alup((size_t)N * HID * 4);
    long stride_elems = (long)(per / 4);
    float* tb = (float*)(base + off);
    bool deferred = (off + (size_t)(K + 1) * per) <= ws_size && K < 60;

    hipMemsetAsync(deg, 0, (size_t)N * 4, stream);
    hipMemsetAsync(fill, 0, (size_t)N * 4, stream);
    hipMemsetAsync(sums, 0, 512 * 4, stream);

    k_coef<<<1, 64, 0, stream>>>(gamma_L, gamma_H, K, cL, cH);
    k_deg<<<cdiv(E, 256), 256, 0, stream>>>(dst, E, deg);
    k_dinv<<<cdiv(N, 256), 256, 0, stream>>>(deg, N, dinv, dinv2, sdeg);
    k_scan<<<1, 1024, 0, stream>>>(deg, N, row_ptr);
    k_scatter<<<cdiv(E, 256), 256, 0, stream>>>(src, dst, E, row_ptr, fill, dinv, csr_src,
                                                csr_w);

    if (deferred) {
        // u_0 = dinv * h, slice-major
        k_gemm_in<<<cdiv(N, 128), 512, 0, stream>>>(x, W_in, b_in, tb, accL, accH, cL, cH,
                                                    dinv, N, IN, 1);
        int nchunks = 256;
        int cpb = cdiv(N, nchunks);
        dim3 pgrid(NSLICE, nchunks);
        for (int j = 1; j <= K; ++j) {
            const float* uin = tb + (long)(j - 1) * stride_elems;
            float* uout = tb + (long)j * stride_elems;
            k_prop_slice<<<pgrid, 256, 0, stream>>>(row_ptr, csr_src, dinv2, uin, uout, N,
                                                    cpb);
        }
        k_combine<<<512, 256, 0, stream>>>(tb, stride_elems, K, sdeg, accL, accH, cL, cH, N,
                                           sums);
    } else {
        float* h = tb;
        float* ta = tb + stride_elems;
        k_gemm_in<<<cdiv(N, 128), 512, 0, stream>>>(x, W_in, b_in, h, accL, accH, cL, cH,
                                                    dinv, N, IN, 0);
        const float* tin = h;
        float* tout = ta;
        for (int j = 1; j <= K; ++j) {
            int write_t = (j < K) ? 1 : 0;
            k_prop<<<cdiv(N, 4), 256, 0, stream>>>(row_ptr, csr_src, csr_w, tin, tout, accL,
                                                   accH, cL, cH, j, N, write_t, 1);
            const float* nt = tout;
            tout = (nt == ta) ? h : ta;
            tin = nt;
        }
        k_stats<<<200, 256, 0, stream>>>(accL, accH, N, sums);
    }

    k_bnfin<<<1, 128, 0, stream>>>(sums, N, bn_scale, bn_shift, a_mul, a_add);
    dim3 gup(cdiv(N, 128), 2);
    k_gemm_up<<<gup, 512, 0, stream>>>(accL, accH, W_up, b_up, a_mul, a_add, out, N);
}

// Round 8
// 989.152 us; speedup vs baseline: 1.5860x; 1.5860x over previous
//
#include <hip/hip_runtime.h>
#include <hip/hip_fp16.h>

#define HIDF 128

typedef float v4f __attribute__((ext_vector_type(4)));
struct alignas(8) half4 { __half2 lo, hi; };

static inline int cdiv(int a, int b) { return (a + b - 1) / b; }
static inline size_t alup(size_t b) { return (b + 255) & ~(size_t)255; }

// ---- degree count over dst ----
__global__ void k_deg(const int* __restrict__ dst, int E, int* __restrict__ deg) {
    int i = blockIdx.x * blockDim.x + threadIdx.x;
    if (i < E) atomicAdd(&deg[dst[i]], 1);
}

// ---- dinv = rsqrt(max(deg,1)) ----
__global__ void k_dinv(const int* __restrict__ deg, int N, float* __restrict__ dinv) {
    int i = blockIdx.x * blockDim.x + threadIdx.x;
    if (i < N) {
        float d = (float)deg[i];
        dinv[i] = rsqrtf(fmaxf(d, 1.0f));
    }
}

// ---- coefficients: cL[j]=gamma_L[j]; cH[j]=(-1)^j sum_{k>=j} gamma_H[k]*C(k,j) ----
__global__ void k_coef(const float* __restrict__ gL, const float* __restrict__ gH, int K,
                       float* __restrict__ cL, float* __restrict__ cH) {
    if (threadIdx.x == 0 && blockIdx.x == 0) {
        for (int j = 0; j <= K; ++j) {
            double s = 0.0;
            double C = 1.0;
            for (int k = j; k <= K; ++k) {
                s += (double)gH[k] * C;
                C = C * (double)(k + 1) / (double)(k + 1 - j);
            }
            cH[j] = (j & 1) ? (float)(-s) : (float)s;
            cL[j] = gL[j];
        }
    }
}

// ---- single-block exclusive scan deg -> row_ptr ----
__global__ __launch_bounds__(1024) void k_scan(const int* __restrict__ deg, int N,
                                               int* __restrict__ row_ptr) {
    __shared__ int ls[1024];
    int tid = threadIdx.x;
    int chunk = (N + 1023) / 1024;
    int start = tid * chunk;
    int end = min(start + chunk, N);
    int s = 0;
    for (int i = start; i < end; ++i) s += deg[i];
    ls[tid] = s;
    __syncthreads();
    for (int off = 1; off < 1024; off <<= 1) {
        int v = (tid >= off) ? ls[tid - off] : 0;
        __syncthreads();
        ls[tid] += v;
        __syncthreads();
    }
    int run = ls[tid] - s;
    for (int i = start; i < end; ++i) {
        row_ptr[i] = run;
        run += deg[i];
    }
    if (tid == 1023) row_ptr[N] = run;
}

// ---- scatter edges into CSR (by dst) ----
__global__ void k_scatter(const int* __restrict__ src, const int* __restrict__ dst, int E,
                          const int* __restrict__ row_ptr, int* __restrict__ fill,
                          const float* __restrict__ dinv, int* __restrict__ csr_src,
                          float* __restrict__ csr_w) {
    int i = blockIdx.x * blockDim.x + threadIdx.x;
    if (i < E) {
        int s = src[i], d = dst[i];
        int pos = row_ptr[d] + atomicAdd(&fill[d], 1);
        csr_src[pos] = s;
        csr_w[pos] = dinv[s] * dinv[d];
    }
}

// ================= GEMM-IN (R5 body; two variants to keep VGPR low) =================
// BM=128, BN=128, BK=20, 512 threads, 8x4 frag, transposed As, single-buffered.

// deferred: epilogue writes u0 = h as fp16 row-major basis vector only
__global__ __launch_bounds__(512) void k_gemm_in_h(
    const float* __restrict__ X, const float* __restrict__ W, const float* __restrict__ b,
    __half* __restrict__ U0, int M, int Kdim) {
    const int BK = 20;
    __shared__ float As[BK][132];
    __shared__ float Bs[BK][128];
    int tid = threadIdx.x;
    int tx = tid & 31, ty = tid >> 5;
    int row0 = blockIdx.x * 128;
    float acc[8][4] = {};
    for (int k0 = 0; k0 < Kdim; k0 += BK) {
        for (int l = tid; l < 640; l += 512) {
            int m = l / 5, q = l % 5;
            int r = row0 + m;
            float4 v = {0.f, 0.f, 0.f, 0.f};
            if (r < M) v = *(const float4*)&X[(long)r * Kdim + k0 + q * 4];
            As[q * 4 + 0][m] = v.x;
            As[q * 4 + 1][m] = v.y;
            As[q * 4 + 2][m] = v.z;
            As[q * 4 + 3][m] = v.w;
        }
        for (int l = tid; l < 640; l += 512) {
            int k = l >> 5, n = (l & 31) * 4;
            *(float4*)&Bs[k][n] = *(const float4*)&W[(long)(k0 + k) * 128 + n];
        }
        __syncthreads();
#pragma unroll
        for (int k = 0; k < BK; ++k) {
            float4 a0 = *(const float4*)&As[k][ty * 8];
            float4 a1 = *(const float4*)&As[k][ty * 8 + 4];
            float4 bb = *(const float4*)&Bs[k][tx * 4];
            float a[8] = {a0.x, a0.y, a0.z, a0.w, a1.x, a1.y, a1.z, a1.w};
#pragma unroll
            for (int i = 0; i < 8; ++i) {
                acc[i][0] += a[i] * bb.x;
                acc[i][1] += a[i] * bb.y;
                acc[i][2] += a[i] * bb.z;
                acc[i][3] += a[i] * bb.w;
            }
        }
        __syncthreads();
    }
    float4 bias = *(const float4*)&b[tx * 4];
    float bv[4] = {bias.x, bias.y, bias.z, bias.w};
#pragma unroll
    for (int i = 0; i < 8; ++i) {
        int r = row0 + ty * 8 + i;
        if (r < M) {
            half4 o;
            o.lo = __float22half2_rn(make_float2(acc[i][0] + bv[0], acc[i][1] + bv[1]));
            o.hi = __float22half2_rn(make_float2(acc[i][2] + bv[2], acc[i][3] + bv[3]));
            *(half4*)&U0[(long)r * HIDF + tx * 4] = o;
        }
    }
}

// fallback: fp32 H + acc init (R5 mode-0)
__global__ __launch_bounds__(512) void k_gemm_in_f(
    const float* __restrict__ X, const float* __restrict__ W, const float* __restrict__ b,
    float* __restrict__ H, float* __restrict__ accL, float* __restrict__ accH,
    const float* __restrict__ cL, const float* __restrict__ cH, int M, int Kdim) {
    const int BK = 20;
    __shared__ float As[BK][132];
    __shared__ float Bs[BK][128];
    int tid = threadIdx.x;
    int tx = tid & 31, ty = tid >> 5;
    int row0 = blockIdx.x * 128;
    float acc[8][4] = {};
    for (int k0 = 0; k0 < Kdim; k0 += BK) {
        for (int l = tid; l < 640; l += 512) {
            int m = l / 5, q = l % 5;
            int r = row0 + m;
            float4 v = {0.f, 0.f, 0.f, 0.f};
            if (r < M) v = *(const float4*)&X[(long)r * Kdim + k0 + q * 4];
            As[q * 4 + 0][m] = v.x;
            As[q * 4 + 1][m] = v.y;
            As[q * 4 + 2][m] = v.z;
            As[q * 4 + 3][m] = v.w;
        }
        for (int l = tid; l < 640; l += 512) {
            int k = l >> 5, n = (l & 31) * 4;
            *(float4*)&Bs[k][n] = *(const float4*)&W[(long)(k0 + k) * 128 + n];
        }
        __syncthreads();
#pragma unroll
        for (int k = 0; k < BK; ++k) {
            float4 a0 = *(const float4*)&As[k][ty * 8];
            float4 a1 = *(const float4*)&As[k][ty * 8 + 4];
            float4 bb = *(const float4*)&Bs[k][tx * 4];
            float a[8] = {a0.x, a0.y, a0.z, a0.w, a1.x, a1.y, a1.z, a1.w};
#pragma unroll
            for (int i = 0; i < 8; ++i) {
                acc[i][0] += a[i] * bb.x;
                acc[i][1] += a[i] * bb.y;
                acc[i][2] += a[i] * bb.z;
                acc[i][3] += a[i] * bb.w;
            }
        }
        __syncthreads();
    }
    float g0 = cL[0], h0 = cH[0];
    float4 bias = *(const float4*)&b[tx * 4];
    float bv[4] = {bias.x, bias.y, bias.z, bias.w};
#pragma unroll
    for (int i = 0; i < 8; ++i) {
        int r = row0 + ty * 8 + i;
        if (r < M) {
            long idx = (long)r * 128 + tx * 4;
            float4 vh;
            float* ph = (float*)&vh;
#pragma unroll
            for (int j = 0; j < 4; ++j) ph[j] = acc[i][j] + bv[j];
            *(float4*)&H[idx] = vh;
            float4 vl = {g0 * vh.x, g0 * vh.y, g0 * vh.z, g0 * vh.w};
            float4 vv = {h0 * vh.x, h0 * vh.y, h0 * vh.z, h0 * vh.w};
            *(float4*)&accL[idx] = vl;
            *(float4*)&accH[idx] = vv;
        }
    }
}

// ---- fp16 prop: t_out = P t_in (basis step, no acc) ----
// one wave per node; half-wave per edge-parity; 4 fp16 feats/lane (8B); fp32 accumulate
__global__ __launch_bounds__(256) void k_prop_h(
    const int* __restrict__ row_ptr, const int* __restrict__ csr_src,
    const float* __restrict__ csr_w, const __half* __restrict__ t_in,
    __half* __restrict__ t_out, int N) {
    int wave = threadIdx.x >> 6;
    int lane = threadIdx.x & 63;
    int half = lane >> 5;
    int l5 = lane & 31;
    int node = blockIdx.x * 4 + wave;
    if (node >= N) return;
    int e0 = row_ptr[node], e1 = row_ptr[node + 1];
    float sx = 0.f, sy = 0.f, sz = 0.f, sw = 0.f;
    int e = e0 + half;
    for (; e + 6 < e1; e += 8) {
        int i0 = csr_src[e], i1 = csr_src[e + 2], i2 = csr_src[e + 4], i3 = csr_src[e + 6];
        float w0 = csr_w[e], w1 = csr_w[e + 2], w2 = csr_w[e + 4], w3 = csr_w[e + 6];
        half4 v0 = *(const half4*)&t_in[(long)i0 * HIDF + l5 * 4];
        half4 v1 = *(const half4*)&t_in[(long)i1 * HIDF + l5 * 4];
        half4 v2 = *(const half4*)&t_in[(long)i2 * HIDF + l5 * 4];
        half4 v3 = *(const half4*)&t_in[(long)i3 * HIDF + l5 * 4];
        float2 a0 = __half22float2(v0.lo), b0 = __half22float2(v0.hi);
        float2 a1 = __half22float2(v1.lo), b1 = __half22float2(v1.hi);
        float2 a2 = __half22float2(v2.lo), b2 = __half22float2(v2.hi);
        float2 a3 = __half22float2(v3.lo), b3 = __half22float2(v3.hi);
        sx += w0 * a0.x + w1 * a1.x + w2 * a2.x + w3 * a3.x;
        sy += w0 * a0.y + w1 * a1.y + w2 * a2.y + w3 * a3.y;
        sz += w0 * b0.x + w1 * b1.x + w2 * b2.x + w3 * b3.x;
        sw += w0 * b0.y + w1 * b1.y + w2 * b2.y + w3 * b3.y;
    }
    for (; e < e1; e += 2) {
        int i0 = csr_src[e];
        float w0 = csr_w[e];
        half4 v0 = *(const half4*)&t_in[(long)i0 * HIDF + l5 * 4];
        float2 a0 = __half22float2(v0.lo), b0 = __half22float2(v0.hi);
        sx += w0 * a0.x;
        sy += w0 * a0.y;
        sz += w0 * b0.x;
        sw += w0 * b0.y;
    }
    sx += __shfl_xor(sx, 32);
    sy += __shfl_xor(sy, 32);
    sz += __shfl_xor(sz, 32);
    sw += __shfl_xor(sw, 32);
    if (half == 0) {
        half4 o;
        o.lo = __float22half2_rn(make_float2(sx, sy));
        o.hi = __float22half2_rn(make_float2(sz, sw));
        *(half4*)&t_out[(long)node * HIDF + l5 * 4] = o;
    }
}

// ---- fallback fp32 prop (R5) ----
__global__ __launch_bounds__(256) void k_prop(
    const int* __restrict__ row_ptr, const int* __restrict__ csr_src,
    const float* __restrict__ csr_w, const float* __restrict__ t_in,
    float* __restrict__ t_out, float* __restrict__ accL, float* __restrict__ accH,
    const float* __restrict__ cL, const float* __restrict__ cH, int j, int N, int write_t) {
    int wave = threadIdx.x >> 6;
    int lane = threadIdx.x & 63;
    int half = lane >> 5;
    int l5 = lane & 31;
    int node = blockIdx.x * 4 + wave;
    if (node >= N) return;
    int e0 = row_ptr[node], e1 = row_ptr[node + 1];
    float sx = 0.f, sy = 0.f, sz = 0.f, sw = 0.f;
    int e = e0 + half;
    for (; e + 6 < e1; e += 8) {
        int i0 = csr_src[e], i1 = csr_src[e + 2], i2 = csr_src[e + 4], i3 = csr_src[e + 6];
        float w0 = csr_w[e], w1 = csr_w[e + 2], w2 = csr_w[e + 4], w3 = csr_w[e + 6];
        float4 v0 = *(const float4*)&t_in[(long)i0 * HIDF + l5 * 4];
        float4 v1 = *(const float4*)&t_in[(long)i1 * HIDF + l5 * 4];
        float4 v2 = *(const float4*)&t_in[(long)i2 * HIDF + l5 * 4];
        float4 v3 = *(const float4*)&t_in[(long)i3 * HIDF + l5 * 4];
        sx += w0 * v0.x + w1 * v1.x + w2 * v2.x + w3 * v3.x;
        sy += w0 * v0.y + w1 * v1.y + w2 * v2.y + w3 * v3.y;
        sz += w0 * v0.z + w1 * v1.z + w2 * v2.z + w3 * v3.z;
        sw += w0 * v0.w + w1 * v1.w + w2 * v2.w + w3 * v3.w;
    }
    for (; e < e1; e += 2) {
        int i0 = csr_src[e];
        float w0 = csr_w[e];
        float4 v0 = *(const float4*)&t_in[(long)i0 * HIDF + l5 * 4];
        sx += w0 * v0.x;
        sy += w0 * v0.y;
        sz += w0 * v0.z;
        sw += w0 * v0.w;
    }
    sx += __shfl_xor(sx, 32);
    sy += __shfl_xor(sy, 32);
    sz += __shfl_xor(sz, 32);
    sw += __shfl_xor(sw, 32);
    if (half == 0) {
        long base = (long)node * HIDF + l5 * 4;
        if (write_t) {
            float4 o = {sx, sy, sz, sw};
            *(float4*)&t_out[base] = o;
        }
        float gL = cL[j], gH = cH[j];
        float4 aL = *(const float4*)&accL[base];
        float4 aH = *(const float4*)&accH[base];
        aL.x += gL * sx; aL.y += gL * sy; aL.z += gL * sz; aL.w += gL * sw;
        aH.x += gH * sx; aH.y += gH * sy; aH.z += gH * sz; aH.w += gH * sw;
        *(float4*)&accL[base] = aL;
        *(float4*)&accH[base] = aH;
    }
}

// ---- fused basis combine + BN stats (fp16 basis) ----
__global__ __launch_bounds__(256) void k_combine_h(
    const __half* __restrict__ tb, long tstride, int K, float* __restrict__ accL,
    float* __restrict__ accH, const float* __restrict__ cL, const float* __restrict__ cH,
    int N, float* __restrict__ sums) {
    int tid = threadIdx.x;
    int l5 = tid & 31;
    int g = tid >> 5;
    float4 s1 = {0, 0, 0, 0}, s2 = {0, 0, 0, 0}, s3 = {0, 0, 0, 0}, s4 = {0, 0, 0, 0};
    for (long r = blockIdx.x * 8 + g; r < N; r += (long)gridDim.x * 8) {
        const __half* p = tb + r * HIDF + l5 * 4;
        float4 aL = {0, 0, 0, 0}, aH = {0, 0, 0, 0};
        for (int j = 0; j <= K; ++j) {
            half4 vh = *(const half4*)(p + (long)j * tstride);
            float2 v01 = __half22float2(vh.lo);
            float2 v23 = __half22float2(vh.hi);
            float gL = cL[j], gH = cH[j];
            aL.x += gL * v01.x; aL.y += gL * v01.y; aL.z += gL * v23.x; aL.w += gL * v23.y;
            aH.x += gH * v01.x; aH.y += gH * v01.y; aH.z += gH * v23.x; aH.w += gH * v23.y;
        }
        long base = r * HIDF + l5 * 4;
        *(float4*)&accL[base] = aL;
        *(float4*)&accH[base] = aH;
        s1.x += aL.x; s1.y += aL.y; s1.z += aL.z; s1.w += aL.w;
        s2.x += aL.x * aL.x; s2.y += aL.y * aL.y; s2.z += aL.z * aL.z; s2.w += aL.w * aL.w;
        s3.x += aH.x; s3.y += aH.y; s3.z += aH.z; s3.w += aH.w;
        s4.x += aH.x * aH.x; s4.y += aH.y * aH.y; s4.z += aH.z * aH.z; s4.w += aH.w * aH.w;
    }
    __shared__ float4 ls1[256], ls2[256], ls3[256], ls4[256];
    ls1[tid] = s1;
    ls2[tid] = s2;
    ls3[tid] = s3;
    ls4[tid] = s4;
    __syncthreads();
    if (tid < 32) {
        float4 a = ls1[tid], bq = ls2[tid], c = ls3[tid], d = ls4[tid];
        for (int gg = 1; gg < 8; ++gg) {
            float4 t;
            t = ls1[gg * 32 + tid]; a.x += t.x; a.y += t.y; a.z += t.z; a.w += t.w;
            t = ls2[gg * 32 + tid]; bq.x += t.x; bq.y += t.y; bq.z += t.z; bq.w += t.w;
            t = ls3[gg * 32 + tid]; c.x += t.x; c.y += t.y; c.z += t.z; c.w += t.w;
            t = ls4[gg * 32 + tid]; d.x += t.x; d.y += t.y; d.z += t.z; d.w += t.w;
        }
        int f = tid * 4;
        atomicAdd(&sums[f + 0], a.x); atomicAdd(&sums[f + 1], a.y);
        atomicAdd(&sums[f + 2], a.z); atomicAdd(&sums[f + 3], a.w);
        atomicAdd(&sums[128 + f + 0], bq.x); atomicAdd(&sums[128 + f + 1], bq.y);
        atomicAdd(&sums[128 + f + 2], bq.z); atomicAdd(&sums[128 + f + 3], bq.w);
        atomicAdd(&sums[256 + f + 0], c.x); atomicAdd(&sums[256 + f + 1], c.y);
        atomicAdd(&sums[256 + f + 2], c.z); atomicAdd(&sums[256 + f + 3], c.w);
        atomicAdd(&sums[384 + f + 0], d.x); atomicAdd(&sums[384 + f + 1], d.y);
        atomicAdd(&sums[384 + f + 2], d.z); atomicAdd(&sums[384 + f + 3], d.w);
    }
}

// ---- standalone BN stats (fallback path) ----
__global__ __launch_bounds__(256) void k_stats(const float* __restrict__ accL,
                                               const float* __restrict__ accH, int N,
                                               float* __restrict__ sums) {
    int tid = threadIdx.x;
    int l5 = tid & 31;
    int g = tid >> 5;
    float4 l1 = {0, 0, 0, 0}, l2 = {0, 0, 0, 0}, h1 = {0, 0, 0, 0}, h2 = {0, 0, 0, 0};
    for (int r = blockIdx.x * 8 + g; r < N; r += gridDim.x * 8) {
        float4 v = *(const float4*)&accL[(long)r * HIDF + l5 * 4];
        l1.x += v.x; l1.y += v.y; l1.z += v.z; l1.w += v.w;
        l2.x += v.x * v.x; l2.y += v.y * v.y; l2.z += v.z * v.z; l2.w += v.w * v.w;
        float4 u = *(const float4*)&accH[(long)r * HIDF + l5 * 4];
        h1.x += u.x; h1.y += u.y; h1.z += u.z; h1.w += u.w;
        h2.x += u.x * u.x; h2.y += u.y * u.y; h2.z += u.z * u.z; h2.w += u.w * u.w;
    }
    __shared__ float4 s1[256], s2[256], s3[256], s4[256];
    s1[tid] = l1; s2[tid] = l2; s3[tid] = h1; s4[tid] = h2;
    __syncthreads();
    if (tid < 32) {
        float4 a = s1[tid], bq = s2[tid], c = s3[tid], d = s4[tid];
        for (int gg = 1; gg < 8; ++gg) {
            float4 t;
            t = s1[gg * 32 + tid]; a.x += t.x; a.y += t.y; a.z += t.z; a.w += t.w;
            t = s2[gg * 32 + tid]; bq.x += t.x; bq.y += t.y; bq.z += t.z; bq.w += t.w;
            t = s3[gg * 32 + tid]; c.x += t.x; c.y += t.y; c.z += t.z; c.w += t.w;
            t = s4[gg * 32 + tid]; d.x += t.x; d.y += t.y; d.z += t.z; d.w += t.w;
        }
        int f = tid * 4;
        atomicAdd(&sums[f + 0], a.x); atomicAdd(&sums[f + 1], a.y);
        atomicAdd(&sums[f + 2], a.z); atomicAdd(&sums[f + 3], a.w);
        atomicAdd(&sums[128 + f + 0], bq.x); atomicAdd(&sums[128 + f + 1], bq.y);
        atomicAdd(&sums[128 + f + 2], bq.z); atomicAdd(&sums[128 + f + 3], bq.w);
        atomicAdd(&sums[256 + f + 0], c.x); atomicAdd(&sums[256 + f + 1], c.y);
        atomicAdd(&sums[256 + f + 2], c.z); atomicAdd(&sums[256 + f + 3], c.w);
        atomicAdd(&sums[384 + f + 0], d.x); atomicAdd(&sums[384 + f + 1], d.y);
        atomicAdd(&sums[384 + f + 2], d.z); atomicAdd(&sums[384 + f + 3], d.w);
    }
}

// ---- finalize BN affine for both encoders ----
__global__ void k_bnfin(const float* __restrict__ sums, int N, const float* __restrict__ scale,
                        const float* __restrict__ shift, float* __restrict__ a_mul,
                        float* __restrict__ a_add) {
    int f = threadIdx.x;
    for (int enc = 0; enc < 2; ++enc) {
        float mu = sums[enc * 256 + f] / (float)N;
        float var = sums[enc * 256 + 128 + f] / (float)N - mu * mu;
        float rstd = rsqrtf(var + 1e-5f);
        float am = rstd * scale[f];
        a_mul[enc * 128 + f] = am;
        a_add[enc * 128 + f] = shift[f] - mu * am;
    }
}

// ---- up GEMM, BN fused at staging, bias+relu; grid.y = encoder ----
__global__ __launch_bounds__(512) void k_gemm_up(
    const float* __restrict__ accL, const float* __restrict__ accH,
    const float* __restrict__ W, const float* __restrict__ bias,
    const float* __restrict__ a_mul, const float* __restrict__ a_add,
    float* __restrict__ out, int M) {
    int enc = blockIdx.y;
    const float* A = enc ? accH : accL;
    float* O = out + (size_t)enc * M * 128;
    __shared__ float As[16][132];
    __shared__ float Bs[16][128];
    __shared__ float ams[128], aas[128];
    int tid = threadIdx.x;
    int tx = tid & 31, ty = tid >> 5;
    int row0 = blockIdx.x * 128;
    if (tid < 128) {
        ams[tid] = a_mul[enc * 128 + tid];
        aas[tid] = a_add[enc * 128 + tid];
    }
    __syncthreads();
    float acc[8][4] = {};
    for (int k0 = 0; k0 < 128; k0 += 16) {
        {
            int m = tid >> 2, q = tid & 3;
            int r = row0 + m;
            float4 v = {0.f, 0.f, 0.f, 0.f};
            if (r < M) v = *(const float4*)&A[(long)r * 128 + k0 + q * 4];
            int kk = q * 4;
            As[kk + 0][m] = v.x * ams[k0 + kk + 0] + aas[k0 + kk + 0];
            As[kk + 1][m] = v.y * ams[k0 + kk + 1] + aas[k0 + kk + 1];
            As[kk + 2][m] = v.z * ams[k0 + kk + 2] + aas[k0 + kk + 2];
            As[kk + 3][m] = v.w * ams[k0 + kk + 3] + aas[k0 + kk + 3];
        }
        {
            int k = tid >> 5, n = (tid & 31) * 4;
            *(float4*)&Bs[k][n] = *(const float4*)&W[(long)(k0 + k) * 128 + n];
        }
        __syncthreads();
#pragma unroll
        for (int k = 0; k < 16; ++k) {
            float4 a0 = *(const float4*)&As[k][ty * 8];
            float4 a1 = *(const float4*)&As[k][ty * 8 + 4];
            float4 bb = *(const float4*)&Bs[k][tx * 4];
            float a[8] = {a0.x, a0.y, a0.z, a0.w, a1.x, a1.y, a1.z, a1.w};
#pragma unroll
            for (int i = 0; i < 8; ++i) {
                acc[i][0] += a[i] * bb.x;
                acc[i][1] += a[i] * bb.y;
                acc[i][2] += a[i] * bb.z;
                acc[i][3] += a[i] * bb.w;
            }
        }
        __syncthreads();
    }
    float4 bv = *(const float4*)&bias[tx * 4];
    float bb[4] = {bv.x, bv.y, bv.z, bv.w};
#pragma unroll
    for (int i = 0; i < 8; ++i) {
        int r = row0 + ty * 8 + i;
        if (r < M) {
            float4 o;
            o.x = fmaxf(acc[i][0] + bb[0], 0.0f);
            o.y = fmaxf(acc[i][1] + bb[1], 0.0f);
            o.z = fmaxf(acc[i][2] + bb[2], 0.0f);
            o.w = fmaxf(acc[i][3] + bb[3], 0.0f);
            *(float4*)&O[(long)r * 128 + tx * 4] = o;
        }
    }
}

extern "C" void kernel_launch(void* const* d_in, const int* in_sizes, int n_in, void* d_out,
                              int out_size, void* d_ws, size_t ws_size, hipStream_t stream) {
    const float* x = (const float*)d_in[0];
    const int* edge_index = (const int*)d_in[1];
    const float* W_in = (const float*)d_in[2];
    const float* b_in = (const float*)d_in[3];
    const float* gamma_L = (const float*)d_in[4];
    const float* gamma_H = (const float*)d_in[5];
    const float* bn_scale = (const float*)d_in[6];
    const float* bn_shift = (const float*)d_in[7];
    const float* W_up = (const float*)d_in[8];
    const float* b_up = (const float*)d_in[9];
    float* out = (float*)d_out;

    const int HID = in_sizes[3];       // 128
    const int IN = in_sizes[2] / HID;  // 500
    const int N = in_sizes[0] / IN;    // 50000
    const int E = in_sizes[1] / 2;     // 800000
    const int K = in_sizes[4] - 1;     // 10

    const int* src = edge_index;
    const int* dst = edge_index + E;

    char* base = (char*)d_ws;
    size_t off = 0;
    auto take = [&](size_t bytes) -> char* {
        char* r = base + off;
        off += alup(bytes);
        return r;
    };
    int* deg = (int*)take((size_t)N * 4);
    int* row_ptr = (int*)take((size_t)(N + 1) * 4);
    int* fill = (int*)take((size_t)N * 4);
    float* dinv = (float*)take((size_t)N * 4);
    int* csr_src = (int*)take((size_t)E * 4);
    float* csr_w = (float*)take((size_t)E * 4);
    float* accL = (float*)take((size_t)N * HID * 4);
    float* accH = (float*)take((size_t)N * HID * 4);
    float* sums = (float*)take(512 * 4);
    float* cL = (float*)take(64 * 4);
    float* cH = (float*)take(64 * 4);
    float* a_mul = (float*)take(256 * 4);
    float* a_add = (float*)take(256 * 4);

    // fp16 basis: K+1 vectors of N*HID halves
    size_t per16 = alup((size_t)N * HID * 2);
    long stride16 = (long)(per16 / 2);  // in halves
    __half* tb16 = (__half*)(base + off);
    bool deferred = (off + (size_t)(K + 1) * per16) <= ws_size && K < 60;
    // fallback: 2 fp32 ping-pong buffers
    size_t per32 = alup((size_t)N * HID * 4);
    long stride32 = (long)(per32 / 4);
    float* fb = (float*)(base + off);
    if (!deferred && off + 2 * per32 > ws_size) deferred = true;  // (shouldn't happen)

    hipMemsetAsync(deg, 0, (size_t)N * 4, stream);
    hipMemsetAsync(fill, 0, (size_t)N * 4, stream);
    hipMemsetAsync(sums, 0, 512 * 4, stream);

    k_coef<<<1, 64, 0, stream>>>(gamma_L, gamma_H, K, cL, cH);
    k_deg<<<cdiv(E, 256), 256, 0, stream>>>(dst, E, deg);
    k_dinv<<<cdiv(N, 256), 256, 0, stream>>>(deg, N, dinv);
    k_scan<<<1, 1024, 0, stream>>>(deg, N, row_ptr);
    k_scatter<<<cdiv(E, 256), 256, 0, stream>>>(src, dst, E, row_ptr, fill, dinv, csr_src,
                                                csr_w);

    if (deferred) {
        k_gemm_in_h<<<cdiv(N, 128), 512, 0, stream>>>(x, W_in, b_in, tb16, N, IN);
        for (int j = 1; j <= K; ++j) {
            const __half* tin = tb16 + (long)(j - 1) * stride16;
            __half* tout = tb16 + (long)j * stride16;
            k_prop_h<<<cdiv(N, 4), 256, 0, stream>>>(row_ptr, csr_src, csr_w, tin, tout, N);
        }
        k_combine_h<<<512, 256, 0, stream>>>(tb16, stride16, K, accL, accH, cL, cH, N, sums);
    } else {
        float* h = fb;
        float* ta = fb + stride32;
        k_gemm_in_f<<<cdiv(N, 128), 512, 0, stream>>>(x, W_in, b_in, h, accL, accH, cL, cH,
                                                      N, IN);
        const float* tin = h;
        float* tout = ta;
        for (int j = 1; j <= K; ++j) {
            int write_t = (j < K) ? 1 : 0;
            k_prop<<<cdiv(N, 4), 256, 0, stream>>>(row_ptr, csr_src, csr_w, tin, tout, accL,
                                                   accH, cL, cH, j, N, write_t);
            const float* nt = tout;
            tout = (nt == ta) ? h : ta;
            tin = nt;
        }
        k_stats<<<200, 256, 0, stream>>>(accL, accH, N, sums);
    }

    k_bnfin<<<1, 128, 0, stream>>>(sums, N, bn_scale, bn_shift, a_mul, a_add);
    dim3 gup(cdiv(N, 128), 2);
    k_gemm_up<<<gup, 512, 0, stream>>>(accL, accH, W_up, b_up, a_mul, a_add, out, N);
}